// Round 1
// baseline (1895.284 us; speedup 1.0000x reference)
//
#include <hip/hip_runtime.h>

#define N_USERS 10000
#define N_ITEMS 40000
#define N_TOTAL 50000
#define HID     64
#define BATCH   8192
#define HOPS    3
#define KDIM    10000          // M == K == 10000 for social GEMM
#define KTILES  157            // ceil(10000/64)
#define KPAD    (KTILES * 64)  // 10048
#define SPLITK  4
#define NSOC    (KTILES * SPLITK)   // 628 social blocks inside fused hop kernel

// output segment offsets (flat f32-element offsets into d_out)
#define O0 0
#define O1 524288
#define O2 1048576
#define O3 1572864
#define O4 2212864
#define O5 2852864
#define O6 3377152
#define O7 3901440
#define O8 4425728
#define O9 4950016
#define O10 5474304

typedef __attribute__((ext_vector_type(8))) short short8;
typedef __attribute__((ext_vector_type(4))) float floatx4;
typedef __attribute__((ext_vector_type(4))) unsigned short ushort4v;
typedef __attribute__((ext_vector_type(8))) unsigned short ushort8v;

__device__ __forceinline__ unsigned short f32bf(float f) {
  union { float f; unsigned u; } v; v.f = f;
  unsigned r = v.u + 0x7fffu + ((v.u >> 16) & 1u);
  return (unsigned short)(r >> 16);
}

// ---------------- fused init: social init | ui init | row histogram ----------------
__global__ __launch_bounds__(256)
void init_all(const float* __restrict__ ue, const float* __restrict__ u1,
              const float* __restrict__ ie, const float* __restrict__ u2,
              const float* __restrict__ i2, const int* __restrict__ Arows,
              int* __restrict__ counts, int nnz,
              float* __restrict__ HS0, float* __restrict__ HS1, float* __restrict__ HSacc,
              float* __restrict__ E0, float* __restrict__ Eacc) {
  int b = blockIdx.x, t = threadIdx.x;
  if (b < 2500) {                               // social: 10000*64 elems
    int i = b * 256 + t;
    int r = i >> 6, c = i & 63;
    float a = ue[i], x = u1[i];
    size_t p = (size_t)r * 128 + c;
    HS0[p] = a; HS0[p + 64] = x;
    HSacc[p] = a; HSacc[p + 64] = x;
    HS1[p] = 0.f; HS1[p + 64] = 0.f;            // hop0 split-K target must be zero
  } else if (b < 15000) {                       // ui: 50000*64 elems
    int i = (b - 2500) * 256 + t;
    int r = i >> 6;
    float a, x;
    if (r < N_USERS) { a = ue[i]; x = u2[i]; }
    else             { a = ie[i - N_USERS * HID]; x = i2[i - N_USERS * HID]; }
    size_t p = (size_t)r * 128 + (i & 63);
    E0[p] = a; E0[p + 64] = x;
    Eacc[p] = a; Eacc[p + 64] = x;
  } else {                                      // histogram of CSR rows
    int i = (b - 15000) * 256 + t;
    if (i < nnz) atomicAdd(&counts[Arows[i]], 1);
  }
}

// ---------------- CSR scan ----------------
__global__ void scan1(const int* __restrict__ counts, int* __restrict__ offs, int* __restrict__ bsum) {
  __shared__ int sh[256];
  int t = threadIdx.x;
  int base = blockIdx.x * 1024 + t * 4;
  int v0 = 0, v1 = 0, v2 = 0, v3 = 0;
  if (base + 0 < N_TOTAL) v0 = counts[base + 0];
  if (base + 1 < N_TOTAL) v1 = counts[base + 1];
  if (base + 2 < N_TOTAL) v2 = counts[base + 2];
  if (base + 3 < N_TOTAL) v3 = counts[base + 3];
  int s = v0 + v1 + v2 + v3;
  sh[t] = s;
  __syncthreads();
  for (int d = 1; d < 256; d <<= 1) {
    int x = (t >= d) ? sh[t - d] : 0;
    __syncthreads();
    sh[t] += x;
    __syncthreads();
  }
  int excl = sh[t] - s;
  if (t == 255) bsum[blockIdx.x] = sh[255];
  if (base + 0 < N_TOTAL) offs[base + 0] = excl; excl += v0;
  if (base + 1 < N_TOTAL) offs[base + 1] = excl; excl += v1;
  if (base + 2 < N_TOTAL) offs[base + 2] = excl; excl += v2;
  if (base + 3 < N_TOTAL) offs[base + 3] = excl;
}

__global__ void scan2(int* __restrict__ bsum, int nb) {  // single block, 64 threads
  __shared__ int sh[64];
  int t = threadIdx.x;
  int v = (t < nb) ? bsum[t] : 0;
  sh[t] = v;
  __syncthreads();
  for (int d = 1; d < 64; d <<= 1) {
    int x = (t >= d) ? sh[t - d] : 0;
    __syncthreads();
    sh[t] += x;
    __syncthreads();
  }
  if (t < nb) bsum[t] = sh[t] - v;  // exclusive
}

// ---------------- transpose (device helper, used fused) ----------------
__device__ __forceinline__ void transpose_dev(int kb, const float* __restrict__ H,
                                              unsigned short* __restrict__ Ht,
                                              float* __restrict__ ts) {
  int k0 = kb * 64;
  int t = threadIdx.x;
#pragma unroll
  for (int i = 0; i < 8; i++) {
    int f = t + i * 256;                 // float4 id 0..2047
    int r = f >> 5, c4 = (f & 31) * 4;
    float4 v = make_float4(0.f, 0.f, 0.f, 0.f);
    if (k0 + r < KDIM) v = *(const float4*)&H[(size_t)(k0 + r) * 128 + c4];
    *(float4*)&ts[r * 132 + c4] = v;
  }
  __syncthreads();
#pragma unroll
  for (int i = 0; i < 4; i++) {
    int g = t + i * 256;                 // 0..1023
    int n = g >> 3, ko = (g & 7) * 8;
    ushort8v o;
#pragma unroll
    for (int j = 0; j < 8; j++) o[j] = f32bf(ts[(ko + j) * 132 + n]);
    *(ushort8v*)&Ht[(size_t)n * KPAD + k0 + ko] = o;
  }
}

// scan3 (CSR offsets finalize) fused with hop-0 transpose (independent work)
__global__ __launch_bounds__(256)
void scan3_tr(int* __restrict__ offs, const int* __restrict__ bexcl,
              int* __restrict__ cursor, int nnz,
              const float* __restrict__ hc, unsigned short* __restrict__ Ht) {
  __shared__ __align__(16) float ts[64 * 132];
  if (blockIdx.x < 196) {
    int i = blockIdx.x * 256 + threadIdx.x;
    if (i < N_TOTAL) {
      int v = offs[i] + bexcl[i >> 10];
      offs[i] = v; cursor[i] = v;
    }
    if (i == 0) offs[N_TOTAL] = nnz;
  } else {
    transpose_dev(blockIdx.x - 196, hc, Ht, ts);
  }
}

__global__ void scatter_csr(const int* __restrict__ rows, const int* __restrict__ cols,
                            const float* __restrict__ vals, int* __restrict__ cursor,
                            int2* __restrict__ edges, int n) {
  int i = blockIdx.x * 256 + threadIdx.x;
  if (i < n) {
    int p = atomicAdd(&cursor[rows[i]], 1);
    edges[p] = make_int2(cols[i], __float_as_int(vals[i]));
  }
}

// ---------------- fused hop: social split-K GEMM (blocks < NSOC) + ui SpMM ----------------
// H==0: reads S (f32, nontemporal), writes bf16 cache Sb. H>=1: reads Sb.
// H==2: social accumulates directly into HSacc; ui skips the dead Eout store.
template<int H>
__global__ __launch_bounds__(256)
void hop_kernel(const float* __restrict__ S, unsigned short* __restrict__ Sb,
                const unsigned short* __restrict__ Bt, float* __restrict__ Cdst,
                const int* __restrict__ offs, const int2* __restrict__ edges,
                const float* __restrict__ Ein, float* __restrict__ Eout,
                float* __restrict__ Eacc) {
  __shared__ __align__(16) unsigned short As[64 * 72];
  __shared__ __align__(16) unsigned short Bs[128 * 72];
  int tid = threadIdx.x;
  if (blockIdx.x < NSOC) {
    // ---- social GEMM block ----
    int mt = blockIdx.x % KTILES;
    int ks = blockIdx.x / KTILES;
    int m0 = mt * 64;
    int t0 = (ks * KTILES) / SPLITK;
    int t1 = ((ks + 1) * KTILES) / SPLITK;
    int wave = tid >> 6, lane = tid & 63;
    int mq = lane & 15, quad = lane >> 4;

    floatx4 acc[8];
#pragma unroll
    for (int i = 0; i < 8; i++) acc[i] = (floatx4){0.f, 0.f, 0.f, 0.f};

    int ar = tid >> 2;                 // 0..63 (A stage row)
    int aq = tid & 3;                  // 0..3
    bool rok = (m0 + ar) < KDIM;
    const float* arow = S + (size_t)(m0 + ar) * KDIM;
    unsigned short* sbrow = Sb + (size_t)(m0 + ar) * KPAD;
    int bn = tid >> 3;                 // 0..31
    int bk = (tid & 7) * 8;            // 0..56

    for (int t = t0; t < t1; ++t) {
      int k0 = t * 64;
      if (H == 0) {
        // stage A: fp32 global -> bf16 LDS, write-through bf16 cache (nontemporal)
#pragma unroll
        for (int i = 0; i < 4; i++) {
          int kk = k0 + aq * 16 + i * 4;
          floatx4 v = (floatx4){0.f, 0.f, 0.f, 0.f};
          if (rok && kk < KDIM) v = __builtin_nontemporal_load((const floatx4*)(arow + kk));
          ushort4v b4;
          b4[0] = f32bf(v[0]); b4[1] = f32bf(v[1]); b4[2] = f32bf(v[2]); b4[3] = f32bf(v[3]);
          *(ushort4v*)&As[ar * 72 + aq * 16 + i * 4] = b4;
          if (rok) __builtin_nontemporal_store(b4, (ushort4v*)&sbrow[kk]);
        }
      } else {
        // stage A: bf16 cached, straight copy (k-pad already zeroed by hop 0)
        int koff = aq * 16;
        ushort8v x0 = {0,0,0,0,0,0,0,0}, x1 = {0,0,0,0,0,0,0,0};
        if (rok) {
          x0 = __builtin_nontemporal_load((const ushort8v*)&sbrow[k0 + koff]);
          x1 = __builtin_nontemporal_load((const ushort8v*)&sbrow[k0 + koff + 8]);
        }
        *(ushort8v*)&As[ar * 72 + koff] = x0;
        *(ushort8v*)&As[ar * 72 + koff + 8] = x1;
      }
      // stage B (bf16 global, pre-transposed, pre-padded; reused across blocks -> cached)
#pragma unroll
      for (int i = 0; i < 4; i++) {
        int n = bn + i * 32;
        *(ushort8v*)&Bs[n * 72 + bk] = *(const ushort8v*)&Bt[(size_t)n * KPAD + k0 + bk];
      }
      __syncthreads();
#pragma unroll
      for (int kk = 0; kk < 64; kk += 32) {
        short8 a = *(const short8*)&As[(wave * 16 + mq) * 72 + kk + quad * 8];
#pragma unroll
        for (int nt = 0; nt < 8; nt++) {
          short8 b = *(const short8*)&Bs[(nt * 16 + mq) * 72 + kk + quad * 8];
          acc[nt] = __builtin_amdgcn_mfma_f32_16x16x32_bf16(a, b, acc[nt], 0, 0, 0);
        }
      }
      __syncthreads();
    }
    // epilogue: split-K atomic accumulate (target zeroed beforehand; H==2 -> HSacc)
#pragma unroll
    for (int nt = 0; nt < 8; nt++) {
      int col = nt * 16 + mq;
      int rbase = m0 + wave * 16 + quad * 4;
#pragma unroll
      for (int i = 0; i < 4; i++) {
        int r = rbase + i;
        if (r < KDIM) atomicAdd(&Cdst[(size_t)r * 128 + col], acc[nt][i]);
      }
    }
  } else {
    // ---- ui SpMM block: one wave per destination row, fused Eacc update ----
    int wid = (blockIdx.x - NSOC) * 4 + (tid >> 6);
    int lane2 = (tid & 63) * 2;
    const float* Einl = Ein + lane2;
    int s = offs[wid], e = offs[wid + 1];
    float ax = 0.f, ay = 0.f;
    int j = s;
    for (; j + 4 <= e; j += 4) {
      int2 e0 = edges[j], e1 = edges[j + 1], e2 = edges[j + 2], e3 = edges[j + 3];
      float2 p0 = *(const float2*)&Einl[(size_t)e0.x * 128];
      float2 p1 = *(const float2*)&Einl[(size_t)e1.x * 128];
      float2 p2 = *(const float2*)&Einl[(size_t)e2.x * 128];
      float2 p3 = *(const float2*)&Einl[(size_t)e3.x * 128];
      float w0 = __int_as_float(e0.y), w1 = __int_as_float(e1.y);
      float w2 = __int_as_float(e2.y), w3 = __int_as_float(e3.y);
      ax += w0 * p0.x + w1 * p1.x + w2 * p2.x + w3 * p3.x;
      ay += w0 * p0.y + w1 * p1.y + w2 * p2.y + w3 * p3.y;
    }
    for (; j < e; ++j) {
      int2 ed = edges[j];
      float2 p = *(const float2*)&Einl[(size_t)ed.x * 128];
      float w = __int_as_float(ed.y);
      ax += w * p.x; ay += w * p.y;
    }
    size_t op = (size_t)wid * 128 + lane2;
    if (H < 2) { float2 o; o.x = ax; o.y = ay; *(float2*)&Eout[op] = o; }
    float2 a = *(float2*)&Eacc[op];
    a.x += ax; a.y += ay;
    *(float2*)&Eacc[op] = a;
  }
}

// ---------------- between-hop prep: transpose next B-tile | HSacc += hc (| zero hn) ----------------
template<int H>   // 1 or 2
__global__ __launch_bounds__(256)
void prep_kernel(const float* __restrict__ hc, unsigned short* __restrict__ Ht,
                 float* __restrict__ HSacc, float* __restrict__ hn) {
  __shared__ __align__(16) float ts[64 * 132];
  if (blockIdx.x < KTILES) {
    transpose_dev(blockIdx.x, hc, Ht, ts);
  } else {
    int i = (blockIdx.x - KTILES) * 256 + threadIdx.x;   // float4 over 10000*128/4
    if (i < (N_USERS * 128) / 4) {
      float4 h = ((const float4*)hc)[i];
      float4 a = ((float4*)HSacc)[i];
      a.x += h.x; a.y += h.y; a.z += h.z; a.w += h.w;
      ((float4*)HSacc)[i] = a;
      if (H == 1) ((float4*)hn)[i] = make_float4(0.f, 0.f, 0.f, 0.f);
    }
  }
}

// ---------------- fused outputs ----------------
__global__ __launch_bounds__(256)
void out_kernel(const int* __restrict__ users, const int* __restrict__ pos,
                const int* __restrict__ neg, const float* __restrict__ HSacc,
                const float* __restrict__ Eacc, const float* __restrict__ item1,
                float* __restrict__ out) {
  if (blockIdx.x < 2500) {
    int i = blockIdx.x * 256 + threadIdx.x;         // over 10000*64
    int r = i >> 6, c = i & 63;
    out[O3 + i] = HSacc[(size_t)r * 128 + c] * 0.25f;
    out[O4 + i] = Eacc[(size_t)r * 128 + c] * 0.25f;
  } else {
    int b = (blockIdx.x - 2500) * 4 + (threadIdx.x >> 6);  // 0..8191
    int lane = threadIdx.x & 63;
    int u = users[b], p = pos[b], n = neg[b];
    const float q = 0.25f;
    float us = HSacc[(size_t)u * 128 + lane] * q;
    float ua = Eacc[(size_t)u * 128 + lane] * q;
    size_t bl = (size_t)b * 64 + lane;
    out[O0 + bl]  = 0.5f * (us + ua);
    out[O1 + bl]  = Eacc[(size_t)(N_USERS + p) * 128 + lane] * q;
    out[O2 + bl]  = Eacc[(size_t)(N_USERS + n) * 128 + lane] * q;
    out[O5 + bl]  = HSacc[(size_t)u * 128 + 64 + lane] * q;
    out[O6 + bl]  = item1[(size_t)p * 64 + lane];
    out[O7 + bl]  = item1[(size_t)n * 64 + lane];
    out[O8 + bl]  = Eacc[(size_t)u * 128 + 64 + lane] * q;
    out[O9 + bl]  = Eacc[(size_t)(N_USERS + p) * 128 + 64 + lane] * q;
    out[O10 + bl] = Eacc[(size_t)(N_USERS + n) * 128 + 64 + lane] * q;
  }
}

extern "C" void kernel_launch(void* const* d_in, const int* in_sizes, int n_in,
                              void* d_out, int out_size, void* d_ws, size_t ws_size,
                              hipStream_t stream) {
  (void)n_in; (void)out_size; (void)ws_size;
  const int*   users = (const int*)d_in[0];
  const int*   pos   = (const int*)d_in[1];
  const int*   neg   = (const int*)d_in[2];
  const float* ue    = (const float*)d_in[3];
  const float* ie    = (const float*)d_in[4];
  const float* u1    = (const float*)d_in[5];
  const float* i1    = (const float*)d_in[6];
  const float* u2    = (const float*)d_in[7];
  const float* i2    = (const float*)d_in[8];
  const float* S     = (const float*)d_in[9];
  const int*   Arows = (const int*)d_in[10];
  const int*   Acols = (const int*)d_in[11];
  const float* Avals = (const float*)d_in[12];
  const int nnz = in_sizes[10];

  char* ws = (char*)d_ws;
  size_t off = 0;
  auto alloc = [&](size_t b) { size_t r = off; off += (b + 255) & ~(size_t)255; return r; };
  float* HS0   = (float*)(ws + alloc(sizeof(float) * (size_t)N_USERS * 128));
  float* HS1   = (float*)(ws + alloc(sizeof(float) * (size_t)N_USERS * 128));
  float* HSacc = (float*)(ws + alloc(sizeof(float) * (size_t)N_USERS * 128));
  unsigned short* Ht = (unsigned short*)(ws + alloc(sizeof(short) * (size_t)128 * KPAD));
  unsigned short* Sb = (unsigned short*)(ws + alloc(sizeof(short) * (size_t)KDIM * KPAD)); // bf16 S cache
  float* E0    = (float*)(ws + alloc(sizeof(float) * (size_t)N_TOTAL * 128));
  float* E1    = (float*)(ws + alloc(sizeof(float) * (size_t)N_TOTAL * 128));
  float* Eacc  = (float*)(ws + alloc(sizeof(float) * (size_t)N_TOTAL * 128));
  int* counts  = (int*)(ws + alloc(sizeof(int) * (N_TOTAL + 16)));
  int* offs    = (int*)(ws + alloc(sizeof(int) * (N_TOTAL + 16)));
  int* cursor  = (int*)(ws + alloc(sizeof(int) * (N_TOTAL + 16)));
  int* bsum    = (int*)(ws + alloc(sizeof(int) * 256));
  int2* edges  = (int2*)(ws + alloc(sizeof(int2) * (size_t)nnz));

  const int histB = (nnz + 255) / 256;

  hipMemsetAsync(counts, 0, sizeof(int) * (N_TOTAL + 16), stream);
  // init social/ui ego tensors + row histogram, one kernel
  init_all<<<15000 + histB, 256, 0, stream>>>(ue, u1, ie, u2, i2, Arows, counts, nnz,
                                              HS0, HS1, HSacc, E0, Eacc);
  scan1<<<49, 256, 0, stream>>>(counts, offs, bsum);
  scan2<<<1, 64, 0, stream>>>(bsum, 49);
  // finalize CSR offsets + transpose hop-0 B tile (independent; fused)
  scan3_tr<<<196 + KTILES, 256, 0, stream>>>(offs, bsum, cursor, nnz, HS0, Ht);
  scatter_csr<<<histB, 256, 0, stream>>>(Arows, Acols, Avals, cursor, edges, nnz);

  // hop 0: social S@h0 (write bf16 S cache) || ui A@e0 (Eacc fused)
  hop_kernel<0><<<NSOC + 12500, 256, 0, stream>>>(S, Sb, Ht, HS1, offs, edges, E0, E1, Eacc);
  // prep 1: HSacc += S h0; zero next target; transpose
  prep_kernel<1><<<KTILES + 1250, 256, 0, stream>>>(HS1, Ht, HSacc, HS0);
  // hop 1
  hop_kernel<1><<<NSOC + 12500, 256, 0, stream>>>(S, Sb, Ht, HS0, offs, edges, E1, E0, Eacc);
  // prep 2: HSacc += S^2 h0; transpose (hop 2 accumulates straight into HSacc)
  prep_kernel<2><<<KTILES + 1250, 256, 0, stream>>>(HS0, Ht, HSacc, HS1);
  // hop 2: social adds into HSacc directly; ui skips dead Eout store
  hop_kernel<2><<<NSOC + 12500, 256, 0, stream>>>(S, Sb, Ht, HSacc, offs, edges, E0, E1, Eacc);

  float* out = (float*)d_out;
  out_kernel<<<2500 + 2048, 256, 0, stream>>>(users, pos, neg, HSacc, Eacc, i1, out);
}

// Round 2
// 1614.201 us; speedup vs baseline: 1.1741x; 1.1741x over previous
//
#include <hip/hip_runtime.h>

#define N_USERS 10000
#define N_ITEMS 40000
#define N_TOTAL 50000
#define HID     64
#define BATCH   8192
#define HOPS    3
#define KDIM    10000          // M == K == 10000 for social GEMM
#define KTILES  157            // ceil(10000/64)
#define KPAD    (KTILES * 64)  // 10048
#define SPLITK  4
#define NSOC    (KTILES * SPLITK)   // 628 social GEMM blocks

// output segment offsets (flat f32-element offsets into d_out)
#define O0 0
#define O1 524288
#define O2 1048576
#define O3 1572864
#define O4 2212864
#define O5 2852864
#define O6 3377152
#define O7 3901440
#define O8 4425728
#define O9 4950016
#define O10 5474304

typedef __attribute__((ext_vector_type(8))) short short8;
typedef __attribute__((ext_vector_type(4))) float floatx4;
typedef __attribute__((ext_vector_type(4))) unsigned short ushort4v;
typedef __attribute__((ext_vector_type(8))) unsigned short ushort8v;

__device__ __forceinline__ unsigned short f32bf(float f) {
  union { float f; unsigned u; } v; v.f = f;
  unsigned r = v.u + 0x7fffu + ((v.u >> 16) & 1u);
  return (unsigned short)(r >> 16);
}

// ---------------- fused init: social init | ui init | row histogram ----------------
__global__ __launch_bounds__(256)
void init_all(const float* __restrict__ ue, const float* __restrict__ u1,
              const float* __restrict__ ie, const float* __restrict__ u2,
              const float* __restrict__ i2, const int* __restrict__ Arows,
              int* __restrict__ counts, int nnz,
              float* __restrict__ HS0, float* __restrict__ HS1, float* __restrict__ HSacc,
              float* __restrict__ E0, float* __restrict__ Eacc) {
  int b = blockIdx.x, t = threadIdx.x;
  if (b < 2500) {                               // social: 10000*64 elems
    int i = b * 256 + t;
    int r = i >> 6, c = i & 63;
    float a = ue[i], x = u1[i];
    size_t p = (size_t)r * 128 + c;
    HS0[p] = a; HS0[p + 64] = x;
    HSacc[p] = a; HSacc[p + 64] = x;
    HS1[p] = 0.f; HS1[p + 64] = 0.f;            // hop0 split-K target must be zero
  } else if (b < 15000) {                       // ui: 50000*64 elems
    int i = (b - 2500) * 256 + t;
    int r = i >> 6;
    float a, x;
    if (r < N_USERS) { a = ue[i]; x = u2[i]; }
    else             { a = ie[i - N_USERS * HID]; x = i2[i - N_USERS * HID]; }
    size_t p = (size_t)r * 128 + (i & 63);
    E0[p] = a; E0[p + 64] = x;
    Eacc[p] = a; Eacc[p + 64] = x;
  } else {                                      // histogram of CSR rows
    int i = (b - 15000) * 256 + t;
    if (i < nnz) atomicAdd(&counts[Arows[i]], 1);
  }
}

// ---------------- CSR scan ----------------
__global__ void scan1(const int* __restrict__ counts, int* __restrict__ offs, int* __restrict__ bsum) {
  __shared__ int sh[256];
  int t = threadIdx.x;
  int base = blockIdx.x * 1024 + t * 4;
  int v0 = 0, v1 = 0, v2 = 0, v3 = 0;
  if (base + 0 < N_TOTAL) v0 = counts[base + 0];
  if (base + 1 < N_TOTAL) v1 = counts[base + 1];
  if (base + 2 < N_TOTAL) v2 = counts[base + 2];
  if (base + 3 < N_TOTAL) v3 = counts[base + 3];
  int s = v0 + v1 + v2 + v3;
  sh[t] = s;
  __syncthreads();
  for (int d = 1; d < 256; d <<= 1) {
    int x = (t >= d) ? sh[t - d] : 0;
    __syncthreads();
    sh[t] += x;
    __syncthreads();
  }
  int excl = sh[t] - s;
  if (t == 255) bsum[blockIdx.x] = sh[255];
  if (base + 0 < N_TOTAL) offs[base + 0] = excl; excl += v0;
  if (base + 1 < N_TOTAL) offs[base + 1] = excl; excl += v1;
  if (base + 2 < N_TOTAL) offs[base + 2] = excl; excl += v2;
  if (base + 3 < N_TOTAL) offs[base + 3] = excl;
}

__global__ void scan2(int* __restrict__ bsum, int nb) {  // single block, 64 threads
  __shared__ int sh[64];
  int t = threadIdx.x;
  int v = (t < nb) ? bsum[t] : 0;
  sh[t] = v;
  __syncthreads();
  for (int d = 1; d < 64; d <<= 1) {
    int x = (t >= d) ? sh[t - d] : 0;
    __syncthreads();
    sh[t] += x;
    __syncthreads();
  }
  if (t < nb) bsum[t] = sh[t] - v;  // exclusive
}

// ---------------- transpose (device helper) ----------------
__device__ __forceinline__ void transpose_dev(int kb, const float* __restrict__ H,
                                              unsigned short* __restrict__ Ht,
                                              float* __restrict__ ts) {
  int k0 = kb * 64;
  int t = threadIdx.x;
#pragma unroll
  for (int i = 0; i < 8; i++) {
    int f = t + i * 256;                 // float4 id 0..2047
    int r = f >> 5, c4 = (f & 31) * 4;
    float4 v = make_float4(0.f, 0.f, 0.f, 0.f);
    if (k0 + r < KDIM) v = *(const float4*)&H[(size_t)(k0 + r) * 128 + c4];
    *(float4*)&ts[r * 132 + c4] = v;
  }
  __syncthreads();
#pragma unroll
  for (int i = 0; i < 4; i++) {
    int g = t + i * 256;                 // 0..1023
    int n = g >> 3, ko = (g & 7) * 8;
    ushort8v o;
#pragma unroll
    for (int j = 0; j < 8; j++) o[j] = f32bf(ts[(ko + j) * 132 + n]);
    *(ushort8v*)&Ht[(size_t)n * KPAD + k0 + ko] = o;
  }
}

// scan3 (CSR offsets finalize) fused with hop-0 transpose (independent work)
__global__ __launch_bounds__(256)
void scan3_tr(int* __restrict__ offs, const int* __restrict__ bexcl,
              int* __restrict__ cursor, int nnz,
              const float* __restrict__ hc, unsigned short* __restrict__ Ht) {
  __shared__ __align__(16) float ts[64 * 132];
  if (blockIdx.x < 196) {
    int i = blockIdx.x * 256 + threadIdx.x;
    if (i < N_TOTAL) {
      int v = offs[i] + bexcl[i >> 10];
      offs[i] = v; cursor[i] = v;
    }
    if (i == 0) offs[N_TOTAL] = nnz;
  } else {
    transpose_dev(blockIdx.x - 196, hc, Ht, ts);
  }
}

__global__ void scatter_csr(const int* __restrict__ rows, const int* __restrict__ cols,
                            const float* __restrict__ vals, int* __restrict__ cursor,
                            int2* __restrict__ edges, int n) {
  int i = blockIdx.x * 256 + threadIdx.x;
  if (i < n) {
    int p = atomicAdd(&cursor[rows[i]], 1);
    edges[p] = make_int2(cols[i], __float_as_int(vals[i]));
  }
}

// ---------------- social split-K GEMM (standalone, streams S/Sb alone) ----------------
// H==0: reads S (f32, nontemporal — stream-once), writes bf16 cache Sb (plain stores,
//       zero-filled K-pad). H>=1: reads Sb (plain loads — L3 retention between hops helps).
// H==2: accumulates directly into HSacc.
template<int H>
__global__ __launch_bounds__(256)
void social_gemm(const float* __restrict__ S, unsigned short* __restrict__ Sb,
                 const unsigned short* __restrict__ Bt, float* __restrict__ Cdst) {
  __shared__ __align__(16) unsigned short As[64 * 72];
  __shared__ __align__(16) unsigned short Bs[128 * 72];
  int tid = threadIdx.x;
  int mt = blockIdx.x % KTILES;
  int ks = blockIdx.x / KTILES;
  int m0 = mt * 64;
  int t0 = (ks * KTILES) / SPLITK;
  int t1 = ((ks + 1) * KTILES) / SPLITK;
  int wave = tid >> 6, lane = tid & 63;
  int mq = lane & 15, quad = lane >> 4;

  floatx4 acc[8];
#pragma unroll
  for (int i = 0; i < 8; i++) acc[i] = (floatx4){0.f, 0.f, 0.f, 0.f};

  int ar = tid >> 2;                 // 0..63 (A stage row)
  int aq = tid & 3;                  // 0..3  (16-elem chunk)
  bool rok = (m0 + ar) < KDIM;
  const float* arow = S + (size_t)(m0 + ar) * KDIM;
  unsigned short* sbrow = Sb + (size_t)(m0 + ar) * KPAD;
  int bn = tid >> 3;                 // 0..31
  int bk = (tid & 7) * 8;            // 0..56

  for (int t = t0; t < t1; ++t) {
    int k0 = t * 64;
    int kk0 = k0 + aq * 16;
    ushort8v x0 = {0, 0, 0, 0, 0, 0, 0, 0}, x1 = {0, 0, 0, 0, 0, 0, 0, 0};
    if (H == 0) {
      if (rok) {
        if (kk0 < KDIM) {            // KDIM % 16 == 0 -> chunk-granular check is exact
          floatx4 v0 = __builtin_nontemporal_load((const floatx4*)(arow + kk0));
          floatx4 v1 = __builtin_nontemporal_load((const floatx4*)(arow + kk0 + 4));
          floatx4 v2 = __builtin_nontemporal_load((const floatx4*)(arow + kk0 + 8));
          floatx4 v3 = __builtin_nontemporal_load((const floatx4*)(arow + kk0 + 12));
          x0[0] = f32bf(v0[0]); x0[1] = f32bf(v0[1]); x0[2] = f32bf(v0[2]); x0[3] = f32bf(v0[3]);
          x0[4] = f32bf(v1[0]); x0[5] = f32bf(v1[1]); x0[6] = f32bf(v1[2]); x0[7] = f32bf(v1[3]);
          x1[0] = f32bf(v2[0]); x1[1] = f32bf(v2[1]); x1[2] = f32bf(v2[2]); x1[3] = f32bf(v2[3]);
          x1[4] = f32bf(v3[0]); x1[5] = f32bf(v3[1]); x1[6] = f32bf(v3[2]); x1[7] = f32bf(v3[3]);
        }
        // write-through bf16 cache; pad chunks store zeros (no poison left in Sb)
        *(ushort8v*)&sbrow[kk0] = x0;
        *(ushort8v*)&sbrow[kk0 + 8] = x1;
      }
    } else {
      if (rok) {
        x0 = *(const ushort8v*)&sbrow[kk0];
        x1 = *(const ushort8v*)&sbrow[kk0 + 8];
      }
    }
    *(ushort8v*)&As[ar * 72 + aq * 16] = x0;
    *(ushort8v*)&As[ar * 72 + aq * 16 + 8] = x1;
    // stage B (bf16 global, pre-transposed, pre-padded; reused across blocks -> cached)
#pragma unroll
    for (int i = 0; i < 4; i++) {
      int n = bn + i * 32;
      *(ushort8v*)&Bs[n * 72 + bk] = *(const ushort8v*)&Bt[(size_t)n * KPAD + k0 + bk];
    }
    __syncthreads();
#pragma unroll
    for (int kk = 0; kk < 64; kk += 32) {
      short8 a = *(const short8*)&As[(wave * 16 + mq) * 72 + kk + quad * 8];
#pragma unroll
      for (int nt = 0; nt < 8; nt++) {
        short8 b = *(const short8*)&Bs[(nt * 16 + mq) * 72 + kk + quad * 8];
        acc[nt] = __builtin_amdgcn_mfma_f32_16x16x32_bf16(a, b, acc[nt], 0, 0, 0);
      }
    }
    __syncthreads();
  }
  // epilogue: split-K atomic accumulate (target zeroed beforehand; H==2 -> HSacc)
#pragma unroll
  for (int nt = 0; nt < 8; nt++) {
    int col = nt * 16 + mq;
    int rbase = m0 + wave * 16 + quad * 4;
#pragma unroll
    for (int i = 0; i < 4; i++) {
      int r = rbase + i;
      if (r < KDIM) atomicAdd(&Cdst[(size_t)r * 128 + col], acc[nt][i]);
    }
  }
}

// ---------------- ui SpMM (standalone, zero LDS -> full occupancy, L3-resident gather) ----------------
template<int LAST>
__global__ __launch_bounds__(256)
void ui_hop(const int* __restrict__ offs, const int2* __restrict__ edges,
            const float* __restrict__ Ein, float* __restrict__ Eout,
            float* __restrict__ Eacc) {
  int wid = blockIdx.x * 4 + (threadIdx.x >> 6);   // row id, grid covers exactly 50000
  int lane2 = (threadIdx.x & 63) * 2;
  const float* Einl = Ein + lane2;
  int s = offs[wid], e = offs[wid + 1];
  float ax = 0.f, ay = 0.f;
  int j = s;
  for (; j + 4 <= e; j += 4) {
    int2 e0 = edges[j], e1 = edges[j + 1], e2 = edges[j + 2], e3 = edges[j + 3];
    float2 p0 = *(const float2*)&Einl[(size_t)e0.x * 128];
    float2 p1 = *(const float2*)&Einl[(size_t)e1.x * 128];
    float2 p2 = *(const float2*)&Einl[(size_t)e2.x * 128];
    float2 p3 = *(const float2*)&Einl[(size_t)e3.x * 128];
    float w0 = __int_as_float(e0.y), w1 = __int_as_float(e1.y);
    float w2 = __int_as_float(e2.y), w3 = __int_as_float(e3.y);
    ax += w0 * p0.x + w1 * p1.x + w2 * p2.x + w3 * p3.x;
    ay += w0 * p0.y + w1 * p1.y + w2 * p2.y + w3 * p3.y;
  }
  for (; j < e; ++j) {
    int2 ed = edges[j];
    float2 p = *(const float2*)&Einl[(size_t)ed.x * 128];
    float w = __int_as_float(ed.y);
    ax += w * p.x; ay += w * p.y;
  }
  size_t op = (size_t)wid * 128 + lane2;
  if (!LAST) { float2 o; o.x = ax; o.y = ay; *(float2*)&Eout[op] = o; }
  float2 a = *(float2*)&Eacc[op];
  a.x += ax; a.y += ay;
  *(float2*)&Eacc[op] = a;
}

// ---------------- between-hop prep: transpose next B-tile | HSacc += hc (| zero hn) ----------------
template<int H>   // 1 or 2
__global__ __launch_bounds__(256)
void prep_kernel(const float* __restrict__ hc, unsigned short* __restrict__ Ht,
                 float* __restrict__ HSacc, float* __restrict__ hn) {
  __shared__ __align__(16) float ts[64 * 132];
  if (blockIdx.x < KTILES) {
    transpose_dev(blockIdx.x, hc, Ht, ts);
  } else {
    int i = (blockIdx.x - KTILES) * 256 + threadIdx.x;   // float4 over 10000*128/4
    if (i < (N_USERS * 128) / 4) {
      float4 h = ((const float4*)hc)[i];
      float4 a = ((float4*)HSacc)[i];
      a.x += h.x; a.y += h.y; a.z += h.z; a.w += h.w;
      ((float4*)HSacc)[i] = a;
      if (H == 1) ((float4*)hn)[i] = make_float4(0.f, 0.f, 0.f, 0.f);
    }
  }
}

// ---------------- fused outputs ----------------
__global__ __launch_bounds__(256)
void out_kernel(const int* __restrict__ users, const int* __restrict__ pos,
                const int* __restrict__ neg, const float* __restrict__ HSacc,
                const float* __restrict__ Eacc, const float* __restrict__ item1,
                float* __restrict__ out) {
  if (blockIdx.x < 2500) {
    int i = blockIdx.x * 256 + threadIdx.x;         // over 10000*64
    int r = i >> 6, c = i & 63;
    out[O3 + i] = HSacc[(size_t)r * 128 + c] * 0.25f;
    out[O4 + i] = Eacc[(size_t)r * 128 + c] * 0.25f;
  } else {
    int b = (blockIdx.x - 2500) * 4 + (threadIdx.x >> 6);  // 0..8191
    int lane = threadIdx.x & 63;
    int u = users[b], p = pos[b], n = neg[b];
    const float q = 0.25f;
    float us = HSacc[(size_t)u * 128 + lane] * q;
    float ua = Eacc[(size_t)u * 128 + lane] * q;
    size_t bl = (size_t)b * 64 + lane;
    out[O0 + bl]  = 0.5f * (us + ua);
    out[O1 + bl]  = Eacc[(size_t)(N_USERS + p) * 128 + lane] * q;
    out[O2 + bl]  = Eacc[(size_t)(N_USERS + n) * 128 + lane] * q;
    out[O5 + bl]  = HSacc[(size_t)u * 128 + 64 + lane] * q;
    out[O6 + bl]  = item1[(size_t)p * 64 + lane];
    out[O7 + bl]  = item1[(size_t)n * 64 + lane];
    out[O8 + bl]  = Eacc[(size_t)u * 128 + 64 + lane] * q;
    out[O9 + bl]  = Eacc[(size_t)(N_USERS + p) * 128 + 64 + lane] * q;
    out[O10 + bl] = Eacc[(size_t)(N_USERS + n) * 128 + 64 + lane] * q;
  }
}

extern "C" void kernel_launch(void* const* d_in, const int* in_sizes, int n_in,
                              void* d_out, int out_size, void* d_ws, size_t ws_size,
                              hipStream_t stream) {
  (void)n_in; (void)out_size; (void)ws_size;
  const int*   users = (const int*)d_in[0];
  const int*   pos   = (const int*)d_in[1];
  const int*   neg   = (const int*)d_in[2];
  const float* ue    = (const float*)d_in[3];
  const float* ie    = (const float*)d_in[4];
  const float* u1    = (const float*)d_in[5];
  const float* i1    = (const float*)d_in[6];
  const float* u2    = (const float*)d_in[7];
  const float* i2    = (const float*)d_in[8];
  const float* S     = (const float*)d_in[9];
  const int*   Arows = (const int*)d_in[10];
  const int*   Acols = (const int*)d_in[11];
  const float* Avals = (const float*)d_in[12];
  const int nnz = in_sizes[10];

  char* ws = (char*)d_ws;
  size_t off = 0;
  auto alloc = [&](size_t b) { size_t r = off; off += (b + 255) & ~(size_t)255; return r; };
  float* HS0   = (float*)(ws + alloc(sizeof(float) * (size_t)N_USERS * 128));
  float* HS1   = (float*)(ws + alloc(sizeof(float) * (size_t)N_USERS * 128));
  float* HSacc = (float*)(ws + alloc(sizeof(float) * (size_t)N_USERS * 128));
  unsigned short* Ht = (unsigned short*)(ws + alloc(sizeof(short) * (size_t)128 * KPAD));
  unsigned short* Sb = (unsigned short*)(ws + alloc(sizeof(short) * (size_t)KDIM * KPAD)); // bf16 S cache
  float* E0    = (float*)(ws + alloc(sizeof(float) * (size_t)N_TOTAL * 128));
  float* E1    = (float*)(ws + alloc(sizeof(float) * (size_t)N_TOTAL * 128));
  float* Eacc  = (float*)(ws + alloc(sizeof(float) * (size_t)N_TOTAL * 128));
  int* counts  = (int*)(ws + alloc(sizeof(int) * (N_TOTAL + 16)));
  int* offs    = (int*)(ws + alloc(sizeof(int) * (N_TOTAL + 16)));
  int* cursor  = (int*)(ws + alloc(sizeof(int) * (N_TOTAL + 16)));
  int* bsum    = (int*)(ws + alloc(sizeof(int) * 256));
  int2* edges  = (int2*)(ws + alloc(sizeof(int2) * (size_t)nnz));

  const int histB = (nnz + 255) / 256;

  hipMemsetAsync(counts, 0, sizeof(int) * (N_TOTAL + 16), stream);
  // init social/ui ego tensors + row histogram, one kernel
  init_all<<<15000 + histB, 256, 0, stream>>>(ue, u1, ie, u2, i2, Arows, counts, nnz,
                                              HS0, HS1, HSacc, E0, Eacc);
  scan1<<<49, 256, 0, stream>>>(counts, offs, bsum);
  scan2<<<1, 64, 0, stream>>>(bsum, 49);
  // finalize CSR offsets + transpose hop-0 B tile (independent; fused)
  scan3_tr<<<196 + KTILES, 256, 0, stream>>>(offs, bsum, cursor, nnz, HS0, Ht);
  scatter_csr<<<histB, 256, 0, stream>>>(Arows, Acols, Avals, cursor, edges, nnz);

  // hop 0: ui first (E0 still cache-hot), then social (streams S alone, fills Sb)
  ui_hop<0><<<12500, 256, 0, stream>>>(offs, edges, E0, E1, Eacc);
  social_gemm<0><<<NSOC, 256, 0, stream>>>(S, Sb, Ht, HS1);
  // prep 1: HSacc += S h0; zero next split-K target; transpose
  prep_kernel<1><<<KTILES + 1250, 256, 0, stream>>>(HS1, Ht, HSacc, HS0);
  // hop 1
  ui_hop<0><<<12500, 256, 0, stream>>>(offs, edges, E1, E0, Eacc);
  social_gemm<1><<<NSOC, 256, 0, stream>>>(S, Sb, Ht, HS0);
  // prep 2: HSacc += S^2 h0; transpose (hop 2 accumulates straight into HSacc)
  prep_kernel<2><<<KTILES + 1250, 256, 0, stream>>>(HS0, Ht, HSacc, HS1);
  // hop 2: ui skips dead Eout store; social adds into HSacc directly
  ui_hop<1><<<12500, 256, 0, stream>>>(offs, edges, E0, E1, Eacc);
  social_gemm<2><<<NSOC, 256, 0, stream>>>(S, Sb, Ht, HSacc);

  float* out = (float*)d_out;
  out_kernel<<<2500 + 2048, 256, 0, stream>>>(users, pos, neg, HSacc, Eacc, i1, out);
}

// Round 3
// 1520.887 us; speedup vs baseline: 1.2462x; 1.0614x over previous
//
#include <hip/hip_runtime.h>

#define N_USERS 10000
#define N_ITEMS 40000
#define N_TOTAL 50000
#define HID     64
#define BATCH   8192
#define HOPS    3
#define KDIM    10000          // M == K == 10000 for social GEMM
#define KTILES  157            // ceil(10000/64)
#define KPAD    (KTILES * 64)  // 10048
#define MTILES  79             // ceil(10000/128) row tiles of 128
#define SPLITK  8
#define NSOC    (MTILES * SPLITK)   // 632 social GEMM blocks

// output segment offsets (flat f32-element offsets into d_out)
#define O0 0
#define O1 524288
#define O2 1048576
#define O3 1572864
#define O4 2212864
#define O5 2852864
#define O6 3377152
#define O7 3901440
#define O8 4425728
#define O9 4950016
#define O10 5474304

typedef __attribute__((ext_vector_type(8))) short short8;
typedef __attribute__((ext_vector_type(4))) float floatx4;

__device__ __forceinline__ unsigned short f32bf(float f) {
  union { float f; unsigned u; } v; v.f = f;
  unsigned r = v.u + 0x7fffu + ((v.u >> 16) & 1u);
  return (unsigned short)(r >> 16);
}

__device__ __forceinline__ short8 cvt8(floatx4 v0, floatx4 v1) {
  short8 o;
  o[0] = (short)f32bf(v0[0]); o[1] = (short)f32bf(v0[1]);
  o[2] = (short)f32bf(v0[2]); o[3] = (short)f32bf(v0[3]);
  o[4] = (short)f32bf(v1[0]); o[5] = (short)f32bf(v1[1]);
  o[6] = (short)f32bf(v1[2]); o[7] = (short)f32bf(v1[3]);
  return o;
}

// ---------------- fused init: social init | ui init | row histogram ----------------
__global__ __launch_bounds__(256)
void init_all(const float* __restrict__ ue, const float* __restrict__ u1,
              const float* __restrict__ ie, const float* __restrict__ u2,
              const float* __restrict__ i2, const int* __restrict__ Arows,
              int* __restrict__ counts, int nnz,
              float* __restrict__ HS0, float* __restrict__ HS1, float* __restrict__ HSacc,
              float* __restrict__ E0, float* __restrict__ Eacc) {
  int b = blockIdx.x, t = threadIdx.x;
  if (b < 2500) {                               // social: 10000*64 elems
    int i = b * 256 + t;
    int r = i >> 6, c = i & 63;
    float a = ue[i], x = u1[i];
    size_t p = (size_t)r * 128 + c;
    HS0[p] = a; HS0[p + 64] = x;
    HSacc[p] = a; HSacc[p + 64] = x;
    HS1[p] = 0.f; HS1[p + 64] = 0.f;            // hop0 split-K target must be zero
  } else if (b < 15000) {                       // ui: 50000*64 elems
    int i = (b - 2500) * 256 + t;
    int r = i >> 6;
    float a, x;
    if (r < N_USERS) { a = ue[i]; x = u2[i]; }
    else             { a = ie[i - N_USERS * HID]; x = i2[i - N_USERS * HID]; }
    size_t p = (size_t)r * 128 + (i & 63);
    E0[p] = a; E0[p + 64] = x;
    Eacc[p] = a; Eacc[p + 64] = x;
  } else {                                      // histogram of CSR rows
    int i = (b - 15000) * 256 + t;
    if (i < nnz) atomicAdd(&counts[Arows[i]], 1);
  }
}

// ---------------- CSR scan ----------------
__global__ void scan1(const int* __restrict__ counts, int* __restrict__ offs, int* __restrict__ bsum) {
  __shared__ int sh[256];
  int t = threadIdx.x;
  int base = blockIdx.x * 1024 + t * 4;
  int v0 = 0, v1 = 0, v2 = 0, v3 = 0;
  if (base + 0 < N_TOTAL) v0 = counts[base + 0];
  if (base + 1 < N_TOTAL) v1 = counts[base + 1];
  if (base + 2 < N_TOTAL) v2 = counts[base + 2];
  if (base + 3 < N_TOTAL) v3 = counts[base + 3];
  int s = v0 + v1 + v2 + v3;
  sh[t] = s;
  __syncthreads();
  for (int d = 1; d < 256; d <<= 1) {
    int x = (t >= d) ? sh[t - d] : 0;
    __syncthreads();
    sh[t] += x;
    __syncthreads();
  }
  int excl = sh[t] - s;
  if (t == 255) bsum[blockIdx.x] = sh[255];
  if (base + 0 < N_TOTAL) offs[base + 0] = excl; excl += v0;
  if (base + 1 < N_TOTAL) offs[base + 1] = excl; excl += v1;
  if (base + 2 < N_TOTAL) offs[base + 2] = excl; excl += v2;
  if (base + 3 < N_TOTAL) offs[base + 3] = excl;
}

__global__ void scan2(int* __restrict__ bsum, int nb) {  // single block, 64 threads
  __shared__ int sh[64];
  int t = threadIdx.x;
  int v = (t < nb) ? bsum[t] : 0;
  sh[t] = v;
  __syncthreads();
  for (int d = 1; d < 64; d <<= 1) {
    int x = (t >= d) ? sh[t - d] : 0;
    __syncthreads();
    sh[t] += x;
    __syncthreads();
  }
  if (t < nb) bsum[t] = sh[t] - v;  // exclusive
}

// ---------------- B-fragment builder (device helper) ----------------
// Bf frag slot: lane l of ((t, nt, kk)) holds B^T[col=nt*16+(l&15)][k=t*64+kk*32+(l>>4)*8+j]
// = H[k][col], 8 consecutive k per lane. Index = ((t*8+nt)*2+kk)*512 + l*8.
__device__ __forceinline__ void bfrag_dev(int t, const float* __restrict__ H,
                                          unsigned short* __restrict__ Bf,
                                          float* __restrict__ ts) {
  int k0 = t * 64;
  int tid = threadIdx.x;
#pragma unroll
  for (int i = 0; i < 8; i++) {
    int f = tid + i * 256;               // float4 id 0..2047
    int r = f >> 5, c4 = (f & 31) * 4;
    float4 v = make_float4(0.f, 0.f, 0.f, 0.f);
    if (k0 + r < KDIM) v = *(const float4*)&H[(size_t)(k0 + r) * 128 + c4];
    *(float4*)&ts[r * 132 + c4] = v;
  }
  __syncthreads();
#pragma unroll
  for (int i = 0; i < 4; i++) {
    int c0 = tid + i * 256;              // chunk id 0..1023
    int nt = c0 >> 7, kk = (c0 >> 6) & 1, l = c0 & 63;
    int quad = l >> 4, mq = l & 15;
    short8 o;
#pragma unroll
    for (int j = 0; j < 8; j++)
      o[j] = (short)f32bf(ts[(kk * 32 + quad * 8 + j) * 132 + nt * 16 + mq]);
    *(short8*)&Bf[(((size_t)t * 8 + nt) * 2 + kk) * 512 + l * 8] = o;
  }
}

// scan3 (CSR offsets finalize) fused with hop-0 B-frag build (independent work)
__global__ __launch_bounds__(256)
void scan3_bf(int* __restrict__ offs, const int* __restrict__ bexcl,
              int* __restrict__ cursor, int nnz,
              const float* __restrict__ hc, unsigned short* __restrict__ Bf) {
  __shared__ __align__(16) float ts[64 * 132];
  if (blockIdx.x < 196) {
    int i = blockIdx.x * 256 + threadIdx.x;
    if (i < N_TOTAL) {
      int v = offs[i] + bexcl[i >> 10];
      offs[i] = v; cursor[i] = v;
    }
    if (i == 0) offs[N_TOTAL] = nnz;
  } else {
    bfrag_dev(blockIdx.x - 196, hc, Bf, ts);
  }
}

__global__ void scatter_csr(const int* __restrict__ rows, const int* __restrict__ cols,
                            const float* __restrict__ vals, int* __restrict__ cursor,
                            int2* __restrict__ edges, int n) {
  int i = blockIdx.x * 256 + threadIdx.x;
  if (i < n) {
    int p = atomicAdd(&cursor[rows[i]], 1);
    edges[p] = make_int2(cols[i], __float_as_int(vals[i]));
  }
}

// ---------------- social split-K GEMM: LDS-free, barrier-free ----------------
// Block = 128 rows x 128 cols x K-slice; 4 waves x 32 rows/wave (2 row-frags).
// A frags: H==0 reads S f32 at frag positions (NT), converts, writes Sbf frag-ordered
//          (zero-filled pads). H>=1 streams Sbf sequentially (1KB/wave coalesced).
// B frags: Bf (2.5 MB, frag-ordered, L2-resident broadcast).
// Sbf slot: ((((mtile*157 + t)*8 + w*2 + rf)*2 + kk)*512 + lane*8
template<int H>
__global__ __launch_bounds__(256)
void social_gemm(const float* __restrict__ S, unsigned short* __restrict__ Sbf,
                 const unsigned short* __restrict__ Bf, float* __restrict__ Cdst) {
  int tid = threadIdx.x;
  int w = tid >> 6, lane = tid & 63;
  int quad = lane >> 4, mq = lane & 15;
  int mtile = blockIdx.x % MTILES;
  int ks = blockIdx.x / MTILES;
  int m0 = mtile * 128;
  int t0 = (ks * KTILES) / SPLITK;
  int t1 = ((ks + 1) * KTILES) / SPLITK;

  floatx4 acc[2][8];
#pragma unroll
  for (int rf = 0; rf < 2; rf++)
#pragma unroll
    for (int nt = 0; nt < 8; nt++) acc[rf][nt] = (floatx4){0.f, 0.f, 0.f, 0.f};

  int r0 = m0 + w * 32 + mq;         // rf=0 row for this lane
  int r1 = r0 + 16;                  // rf=1 row
  const float* sr0 = S + (size_t)r0 * KDIM;
  const float* sr1 = S + (size_t)r1 * KDIM;
  // frag-slot bases (ushort units)
  size_t sb = (((size_t)mtile * KTILES) * 8 + w * 2) * 1024 + (size_t)lane * 8;

  for (int t = t0; t < t1; ++t) {
    short8 a00, a01, a10, a11;       // a[rf][kk]
    size_t st = sb + (size_t)t * 8192;
    if (H == 0) {
      int kb = t * 64 + quad * 8;
      a00 = a01 = a10 = a11 = (short8){0, 0, 0, 0, 0, 0, 0, 0};
      {
        int k = kb;
        if (r0 < KDIM && k < KDIM)
          a00 = cvt8(__builtin_nontemporal_load((const floatx4*)(sr0 + k)),
                     __builtin_nontemporal_load((const floatx4*)(sr0 + k + 4)));
        k = kb + 32;
        if (r0 < KDIM && k < KDIM)
          a01 = cvt8(__builtin_nontemporal_load((const floatx4*)(sr0 + k)),
                     __builtin_nontemporal_load((const floatx4*)(sr0 + k + 4)));
        k = kb;
        if (r1 < KDIM && k < KDIM)
          a10 = cvt8(__builtin_nontemporal_load((const floatx4*)(sr1 + k)),
                     __builtin_nontemporal_load((const floatx4*)(sr1 + k + 4)));
        k = kb + 32;
        if (r1 < KDIM && k < KDIM)
          a11 = cvt8(__builtin_nontemporal_load((const floatx4*)(sr1 + k)),
                     __builtin_nontemporal_load((const floatx4*)(sr1 + k + 4)));
      }
      *(short8*)&Sbf[st]        = a00;   // (rf=0,kk=0)
      *(short8*)&Sbf[st + 512]  = a01;   // (rf=0,kk=1)
      *(short8*)&Sbf[st + 1024] = a10;   // (rf=1,kk=0)
      *(short8*)&Sbf[st + 1536] = a11;   // (rf=1,kk=1)
    } else {
      a00 = *(const short8*)&Sbf[st];
      a01 = *(const short8*)&Sbf[st + 512];
      a10 = *(const short8*)&Sbf[st + 1024];
      a11 = *(const short8*)&Sbf[st + 1536];
    }
    const unsigned short* bfb = Bf + (size_t)t * 8192 + lane * 8;
#pragma unroll
    for (int kk = 0; kk < 2; kk++) {
      short8 b[8];
#pragma unroll
      for (int nt = 0; nt < 8; nt++)
        b[nt] = *(const short8*)&bfb[((size_t)nt * 2 + kk) * 512];
      short8 ax0 = kk ? a01 : a00;
      short8 ax1 = kk ? a11 : a10;
#pragma unroll
      for (int nt = 0; nt < 8; nt++) {
        acc[0][nt] = __builtin_amdgcn_mfma_f32_16x16x32_bf16(ax0, b[nt], acc[0][nt], 0, 0, 0);
        acc[1][nt] = __builtin_amdgcn_mfma_f32_16x16x32_bf16(ax1, b[nt], acc[1][nt], 0, 0, 0);
      }
    }
  }
  // epilogue: split-K atomic accumulate (target zeroed beforehand; H==2 -> HSacc)
#pragma unroll
  for (int rf = 0; rf < 2; rf++) {
    int rb = m0 + w * 32 + rf * 16 + quad * 4;
#pragma unroll
    for (int nt = 0; nt < 8; nt++) {
      int col = nt * 16 + mq;
#pragma unroll
      for (int i = 0; i < 4; i++) {
        int r = rb + i;
        if (r < KDIM) atomicAdd(&Cdst[(size_t)r * 128 + col], acc[rf][nt][i]);
      }
    }
  }
}

// ---------------- ui SpMM (standalone, zero LDS -> full occupancy, L3-resident gather) ----------------
template<int LAST>
__global__ __launch_bounds__(256)
void ui_hop(const int* __restrict__ offs, const int2* __restrict__ edges,
            const float* __restrict__ Ein, float* __restrict__ Eout,
            float* __restrict__ Eacc) {
  int wid = blockIdx.x * 4 + (threadIdx.x >> 6);   // row id, grid covers exactly 50000
  int lane2 = (threadIdx.x & 63) * 2;
  const float* Einl = Ein + lane2;
  int s = offs[wid], e = offs[wid + 1];
  float ax = 0.f, ay = 0.f;
  int j = s;
  for (; j + 4 <= e; j += 4) {
    int2 e0 = edges[j], e1 = edges[j + 1], e2 = edges[j + 2], e3 = edges[j + 3];
    float2 p0 = *(const float2*)&Einl[(size_t)e0.x * 128];
    float2 p1 = *(const float2*)&Einl[(size_t)e1.x * 128];
    float2 p2 = *(const float2*)&Einl[(size_t)e2.x * 128];
    float2 p3 = *(const float2*)&Einl[(size_t)e3.x * 128];
    float w0 = __int_as_float(e0.y), w1 = __int_as_float(e1.y);
    float w2 = __int_as_float(e2.y), w3 = __int_as_float(e3.y);
    ax += w0 * p0.x + w1 * p1.x + w2 * p2.x + w3 * p3.x;
    ay += w0 * p0.y + w1 * p1.y + w2 * p2.y + w3 * p3.y;
  }
  for (; j < e; ++j) {
    int2 ed = edges[j];
    float2 p = *(const float2*)&Einl[(size_t)ed.x * 128];
    float w = __int_as_float(ed.y);
    ax += w * p.x; ay += w * p.y;
  }
  size_t op = (size_t)wid * 128 + lane2;
  if (!LAST) { float2 o; o.x = ax; o.y = ay; *(float2*)&Eout[op] = o; }
  float2 a = *(float2*)&Eacc[op];
  a.x += ax; a.y += ay;
  *(float2*)&Eacc[op] = a;
}

// ---------------- between-hop prep: B-frag build | HSacc += hc (| zero hn) ----------------
template<int H>   // 1 or 2
__global__ __launch_bounds__(256)
void prep_kernel(const float* __restrict__ hc, unsigned short* __restrict__ Bf,
                 float* __restrict__ HSacc, float* __restrict__ hn) {
  __shared__ __align__(16) float ts[64 * 132];
  if (blockIdx.x < KTILES) {
    bfrag_dev(blockIdx.x, hc, Bf, ts);
  } else {
    int i = (blockIdx.x - KTILES) * 256 + threadIdx.x;   // float4 over 10000*128/4
    if (i < (N_USERS * 128) / 4) {
      float4 h = ((const float4*)hc)[i];
      float4 a = ((float4*)HSacc)[i];
      a.x += h.x; a.y += h.y; a.z += h.z; a.w += h.w;
      ((float4*)HSacc)[i] = a;
      if (H == 1) ((float4*)hn)[i] = make_float4(0.f, 0.f, 0.f, 0.f);
    }
  }
}

// ---------------- fused outputs ----------------
__global__ __launch_bounds__(256)
void out_kernel(const int* __restrict__ users, const int* __restrict__ pos,
                const int* __restrict__ neg, const float* __restrict__ HSacc,
                const float* __restrict__ Eacc, const float* __restrict__ item1,
                float* __restrict__ out) {
  if (blockIdx.x < 2500) {
    int i = blockIdx.x * 256 + threadIdx.x;         // over 10000*64
    int r = i >> 6, c = i & 63;
    out[O3 + i] = HSacc[(size_t)r * 128 + c] * 0.25f;
    out[O4 + i] = Eacc[(size_t)r * 128 + c] * 0.25f;
  } else {
    int b = (blockIdx.x - 2500) * 4 + (threadIdx.x >> 6);  // 0..8191
    int lane = threadIdx.x & 63;
    int u = users[b], p = pos[b], n = neg[b];
    const float q = 0.25f;
    float us = HSacc[(size_t)u * 128 + lane] * q;
    float ua = Eacc[(size_t)u * 128 + lane] * q;
    size_t bl = (size_t)b * 64 + lane;
    out[O0 + bl]  = 0.5f * (us + ua);
    out[O1 + bl]  = Eacc[(size_t)(N_USERS + p) * 128 + lane] * q;
    out[O2 + bl]  = Eacc[(size_t)(N_USERS + n) * 128 + lane] * q;
    out[O5 + bl]  = HSacc[(size_t)u * 128 + 64 + lane] * q;
    out[O6 + bl]  = item1[(size_t)p * 64 + lane];
    out[O7 + bl]  = item1[(size_t)n * 64 + lane];
    out[O8 + bl]  = Eacc[(size_t)u * 128 + 64 + lane] * q;
    out[O9 + bl]  = Eacc[(size_t)(N_USERS + p) * 128 + 64 + lane] * q;
    out[O10 + bl] = Eacc[(size_t)(N_USERS + n) * 128 + 64 + lane] * q;
  }
}

extern "C" void kernel_launch(void* const* d_in, const int* in_sizes, int n_in,
                              void* d_out, int out_size, void* d_ws, size_t ws_size,
                              hipStream_t stream) {
  (void)n_in; (void)out_size; (void)ws_size;
  const int*   users = (const int*)d_in[0];
  const int*   pos   = (const int*)d_in[1];
  const int*   neg   = (const int*)d_in[2];
  const float* ue    = (const float*)d_in[3];
  const float* ie    = (const float*)d_in[4];
  const float* u1    = (const float*)d_in[5];
  const float* i1    = (const float*)d_in[6];
  const float* u2    = (const float*)d_in[7];
  const float* i2    = (const float*)d_in[8];
  const float* S     = (const float*)d_in[9];
  const int*   Arows = (const int*)d_in[10];
  const int*   Acols = (const int*)d_in[11];
  const float* Avals = (const float*)d_in[12];
  const int nnz = in_sizes[10];

  char* ws = (char*)d_ws;
  size_t off = 0;
  auto alloc = [&](size_t b) { size_t r = off; off += (b + 255) & ~(size_t)255; return r; };
  float* HS0   = (float*)(ws + alloc(sizeof(float) * (size_t)N_USERS * 128));
  float* HS1   = (float*)(ws + alloc(sizeof(float) * (size_t)N_USERS * 128));
  float* HSacc = (float*)(ws + alloc(sizeof(float) * (size_t)N_USERS * 128));
  unsigned short* Bf  = (unsigned short*)(ws + alloc(sizeof(short) * (size_t)KTILES * 8192));
  unsigned short* Sbf = (unsigned short*)(ws + alloc(sizeof(short) * (size_t)MTILES * KTILES * 8192));
  float* E0    = (float*)(ws + alloc(sizeof(float) * (size_t)N_TOTAL * 128));
  float* E1    = (float*)(ws + alloc(sizeof(float) * (size_t)N_TOTAL * 128));
  float* Eacc  = (float*)(ws + alloc(sizeof(float) * (size_t)N_TOTAL * 128));
  int* counts  = (int*)(ws + alloc(sizeof(int) * (N_TOTAL + 16)));
  int* offs    = (int*)(ws + alloc(sizeof(int) * (N_TOTAL + 16)));
  int* cursor  = (int*)(ws + alloc(sizeof(int) * (N_TOTAL + 16)));
  int* bsum    = (int*)(ws + alloc(sizeof(int) * 256));
  int2* edges  = (int2*)(ws + alloc(sizeof(int2) * (size_t)nnz));

  const int histB = (nnz + 255) / 256;

  hipMemsetAsync(counts, 0, sizeof(int) * (N_TOTAL + 16), stream);
  // init social/ui ego tensors + row histogram, one kernel
  init_all<<<15000 + histB, 256, 0, stream>>>(ue, u1, ie, u2, i2, Arows, counts, nnz,
                                              HS0, HS1, HSacc, E0, Eacc);
  scan1<<<49, 256, 0, stream>>>(counts, offs, bsum);
  scan2<<<1, 64, 0, stream>>>(bsum, 49);
  // finalize CSR offsets + build hop-0 B-frags (independent; fused)
  scan3_bf<<<196 + KTILES, 256, 0, stream>>>(offs, bsum, cursor, nnz, HS0, Bf);
  scatter_csr<<<histB, 256, 0, stream>>>(Arows, Acols, Avals, cursor, edges, nnz);

  // hop 0: ui first (E0 cache-hot), then social (streams S alone, fills frag-ordered Sbf)
  ui_hop<0><<<12500, 256, 0, stream>>>(offs, edges, E0, E1, Eacc);
  social_gemm<0><<<NSOC, 256, 0, stream>>>(S, Sbf, Bf, HS1);
  // prep 1: HSacc += S h0; zero next split-K target; rebuild B-frags
  prep_kernel<1><<<KTILES + 1250, 256, 0, stream>>>(HS1, Bf, HSacc, HS0);
  // hop 1
  ui_hop<0><<<12500, 256, 0, stream>>>(offs, edges, E1, E0, Eacc);
  social_gemm<1><<<NSOC, 256, 0, stream>>>(S, Sbf, Bf, HS0);
  // prep 2: HSacc += S^2 h0; rebuild B-frags (hop 2 accumulates straight into HSacc)
  prep_kernel<2><<<KTILES + 1250, 256, 0, stream>>>(HS0, Bf, HSacc, HS1);
  // hop 2: ui skips dead Eout store; social adds into HSacc directly
  ui_hop<1><<<12500, 256, 0, stream>>>(offs, edges, E0, E1, Eacc);
  social_gemm<2><<<NSOC, 256, 0, stream>>>(S, Sbf, Bf, HSacc);

  float* out = (float*)d_out;
  out_kernel<<<2500 + 2048, 256, 0, stream>>>(users, pos, neg, HSacc, Eacc, i1, out);
}

// Round 4
// 1385.921 us; speedup vs baseline: 1.3675x; 1.0974x over previous
//
#include <hip/hip_runtime.h>

#define N_USERS 10000
#define N_ITEMS 40000
#define N_TOTAL 50000
#define HID     64
#define BATCH   8192
#define HOPS    3
#define KDIM    10000          // M == K == 10000 for social GEMM
#define KTILES  157            // ceil(10000/64)
#define KPAD    (KTILES * 64)  // 10048
#define MTILES  79             // ceil(10000/128) row tiles of 128
#define SPLITK  8
#define NSOC    (MTILES * SPLITK)   // 632 social GEMM blocks
#define CP_STRIDE ((size_t)MTILES * 16384)   // floats per split-K slice

// output segment offsets (flat f32-element offsets into d_out)
#define O0 0
#define O1 524288
#define O2 1048576
#define O3 1572864
#define O4 2212864
#define O5 2852864
#define O6 3377152
#define O7 3901440
#define O8 4425728
#define O9 4950016
#define O10 5474304

typedef __attribute__((ext_vector_type(8))) short short8;
typedef __attribute__((ext_vector_type(4))) float floatx4;

__device__ __forceinline__ unsigned short f32bf(float f) {
  union { float f; unsigned u; } v; v.f = f;
  unsigned r = v.u + 0x7fffu + ((v.u >> 16) & 1u);
  return (unsigned short)(r >> 16);
}

__device__ __forceinline__ unsigned packbf2(float x, float y) {
  return (unsigned)f32bf(x) | ((unsigned)f32bf(y) << 16);
}

__device__ __forceinline__ short8 cvt8(floatx4 v0, floatx4 v1) {
  short8 o;
  o[0] = (short)f32bf(v0[0]); o[1] = (short)f32bf(v0[1]);
  o[2] = (short)f32bf(v0[2]); o[3] = (short)f32bf(v0[3]);
  o[4] = (short)f32bf(v1[0]); o[5] = (short)f32bf(v1[1]);
  o[6] = (short)f32bf(v1[2]); o[7] = (short)f32bf(v1[3]);
  return o;
}

// ---------------- fused init: social init | ui init (bf16-packed) | row histogram ----------------
__global__ __launch_bounds__(256)
void init_all(const float* __restrict__ ue, const float* __restrict__ u1,
              const float* __restrict__ ie, const float* __restrict__ u2,
              const float* __restrict__ i2, const int* __restrict__ Arows,
              int* __restrict__ counts, int nnz,
              float* __restrict__ HS0, float* __restrict__ HSacc,
              unsigned* __restrict__ Eb0, float* __restrict__ Eacc) {
  int b = blockIdx.x, t = threadIdx.x;
  if (b < 2500) {                               // social: 10000*64 elems
    int i = b * 256 + t;
    int r = i >> 6, c = i & 63;
    float a = ue[i], x = u1[i];
    size_t p = (size_t)r * 128 + c;
    HS0[p] = a; HS0[p + 64] = x;
    HSacc[p] = a; HSacc[p + 64] = x;
  } else if (b < 8750) {                        // ui: 50000*32 dim-pairs
    int i = (b - 2500) * 256 + t;               // pair id
    int r = i >> 5, c2 = (i & 31) * 2;
    const float* srcA; const float* srcB;
    if (r < N_USERS) { srcA = ue + (size_t)r * 64 + c2; srcB = u2 + (size_t)r * 64 + c2; }
    else { srcA = ie + (size_t)(r - N_USERS) * 64 + c2; srcB = i2 + (size_t)(r - N_USERS) * 64 + c2; }
    float2 a = *(const float2*)srcA;
    float2 x = *(const float2*)srcB;
    size_t p = (size_t)r * 128 + c2;
    *(float2*)&Eacc[p] = a;
    *(float2*)&Eacc[p + 64] = x;
    Eb0[(size_t)r * 64 + (c2 >> 1)] = packbf2(a.x, a.y);
    Eb0[(size_t)r * 64 + 32 + (c2 >> 1)] = packbf2(x.x, x.y);
  } else {                                      // histogram of CSR rows
    int i = (b - 8750) * 256 + t;
    if (i < nnz) atomicAdd(&counts[Arows[i]], 1);
  }
}

// ---------------- CSR scan ----------------
__global__ void scan1(const int* __restrict__ counts, int* __restrict__ offs, int* __restrict__ bsum) {
  __shared__ int sh[256];
  int t = threadIdx.x;
  int base = blockIdx.x * 1024 + t * 4;
  int v0 = 0, v1 = 0, v2 = 0, v3 = 0;
  if (base + 0 < N_TOTAL) v0 = counts[base + 0];
  if (base + 1 < N_TOTAL) v1 = counts[base + 1];
  if (base + 2 < N_TOTAL) v2 = counts[base + 2];
  if (base + 3 < N_TOTAL) v3 = counts[base + 3];
  int s = v0 + v1 + v2 + v3;
  sh[t] = s;
  __syncthreads();
  for (int d = 1; d < 256; d <<= 1) {
    int x = (t >= d) ? sh[t - d] : 0;
    __syncthreads();
    sh[t] += x;
    __syncthreads();
  }
  int excl = sh[t] - s;
  if (t == 255) bsum[blockIdx.x] = sh[255];
  if (base + 0 < N_TOTAL) offs[base + 0] = excl; excl += v0;
  if (base + 1 < N_TOTAL) offs[base + 1] = excl; excl += v1;
  if (base + 2 < N_TOTAL) offs[base + 2] = excl; excl += v2;
  if (base + 3 < N_TOTAL) offs[base + 3] = excl;
}

__global__ void scan2(int* __restrict__ bsum, int nb) {  // single block, 64 threads
  __shared__ int sh[64];
  int t = threadIdx.x;
  int v = (t < nb) ? bsum[t] : 0;
  sh[t] = v;
  __syncthreads();
  for (int d = 1; d < 64; d <<= 1) {
    int x = (t >= d) ? sh[t - d] : 0;
    __syncthreads();
    sh[t] += x;
    __syncthreads();
  }
  if (t < nb) bsum[t] = sh[t] - v;  // exclusive
}

// ---------------- B-fragment builders ----------------
// Bf frag slot: lane l of ((t, nt, kk)) holds B^T[col=nt*16+(l&15)][k=t*64+kk*32+(l>>4)*8+j]
// Index = ((t*8+nt)*2+kk)*512 + l*8.
__device__ __forceinline__ void bfrag_emit(int t, const float* __restrict__ ts,
                                           unsigned short* __restrict__ Bf) {
  int tid = threadIdx.x;
#pragma unroll
  for (int i = 0; i < 4; i++) {
    int c0 = tid + i * 256;              // chunk id 0..1023
    int nt = c0 >> 7, kk = (c0 >> 6) & 1, l = c0 & 63;
    int quad = l >> 4, mq = l & 15;
    short8 o;
#pragma unroll
    for (int j = 0; j < 8; j++)
      o[j] = (short)f32bf(ts[(kk * 32 + quad * 8 + j) * 132 + nt * 16 + mq]);
    *(short8*)&Bf[(((size_t)t * 8 + nt) * 2 + kk) * 512 + l * 8] = o;
  }
}

// from a row-major f32 H [KDIM][128]
__device__ __forceinline__ void bfrag_from_h(int t, const float* __restrict__ H,
                                             unsigned short* __restrict__ Bf,
                                             float* __restrict__ ts) {
  int k0 = t * 64;
  int tid = threadIdx.x;
#pragma unroll
  for (int i = 0; i < 8; i++) {
    int f = tid + i * 256;               // float4 id 0..2047
    int r = f >> 5, c4 = (f & 31) * 4;
    float4 v = make_float4(0.f, 0.f, 0.f, 0.f);
    if (k0 + r < KDIM) v = *(const float4*)&H[(size_t)(k0 + r) * 128 + c4];
    *(float4*)&ts[r * 132 + c4] = v;
  }
  __syncthreads();
  bfrag_emit(t, ts, Bf);
}

// from split-K partials: h[r][c] = sum_ks Cpart[ks*MTILES + r/128][r%128][c]
__device__ __forceinline__ void bfrag_from_parts(int t, const float* __restrict__ Cpart,
                                                 unsigned short* __restrict__ Bf,
                                                 float* __restrict__ ts) {
  int k0 = t * 64;
  int tid = threadIdx.x;
#pragma unroll
  for (int i = 0; i < 8; i++) {
    int f = tid + i * 256;               // float4 id 0..2047
    int r = f >> 5, c4 = (f & 31) * 4;
    float4 v = make_float4(0.f, 0.f, 0.f, 0.f);
    int gk = k0 + r;
    if (gk < KDIM) {
      const float* p = Cpart + (size_t)(gk >> 7) * 16384 + (size_t)(gk & 127) * 128 + c4;
#pragma unroll
      for (int ks = 0; ks < SPLITK; ks++) {
        float4 q = *(const float4*)p; p += CP_STRIDE;
        v.x += q.x; v.y += q.y; v.z += q.z; v.w += q.w;
      }
    }
    *(float4*)&ts[r * 132 + c4] = v;
  }
  __syncthreads();
  bfrag_emit(t, ts, Bf);
}

// scan3 (CSR offsets finalize) fused with hop-0 B-frag build (independent work)
__global__ __launch_bounds__(256)
void scan3_bf(int* __restrict__ offs, const int* __restrict__ bexcl,
              int* __restrict__ cursor, int nnz,
              const float* __restrict__ hc, unsigned short* __restrict__ Bf) {
  __shared__ __align__(16) float ts[64 * 132];
  if (blockIdx.x < 196) {
    int i = blockIdx.x * 256 + threadIdx.x;
    if (i < N_TOTAL) {
      int v = offs[i] + bexcl[i >> 10];
      offs[i] = v; cursor[i] = v;
    }
    if (i == 0) offs[N_TOTAL] = nnz;
  } else {
    bfrag_from_h(blockIdx.x - 196, hc, Bf, ts);
  }
}

__global__ void scatter_csr(const int* __restrict__ rows, const int* __restrict__ cols,
                            const float* __restrict__ vals, int* __restrict__ cursor,
                            int2* __restrict__ edges, int n) {
  int i = blockIdx.x * 256 + threadIdx.x;
  if (i < n) {
    int p = atomicAdd(&cursor[rows[i]], 1);
    edges[p] = make_int2(cols[i], __float_as_int(vals[i]));
  }
}

// ---------------- social split-K GEMM: LDS-free, barrier-free, atomic-free ----------------
// Block = 128 rows x 128 cols x K-slice; 4 waves x 32 rows/wave (2 row-frags).
// FIRST: reads S f32 at frag positions (NT), converts, writes Sbf frag-ordered (pads zeroed).
// else: streams Sbf sequentially (1KB/wave coalesced).
// Epilogue: plain stores of the 128x128 tile into this block's private Cpart slot.
template<int FIRST>
__global__ __launch_bounds__(256)
void social_gemm(const float* __restrict__ S, unsigned short* __restrict__ Sbf,
                 const unsigned short* __restrict__ Bf, float* __restrict__ Cpart) {
  int tid = threadIdx.x;
  int w = tid >> 6, lane = tid & 63;
  int quad = lane >> 4, mq = lane & 15;
  int mtile = blockIdx.x % MTILES;
  int ks = blockIdx.x / MTILES;
  int m0 = mtile * 128;
  int t0 = (ks * KTILES) / SPLITK;
  int t1 = ((ks + 1) * KTILES) / SPLITK;

  floatx4 acc[2][8];
#pragma unroll
  for (int rf = 0; rf < 2; rf++)
#pragma unroll
    for (int nt = 0; nt < 8; nt++) acc[rf][nt] = (floatx4){0.f, 0.f, 0.f, 0.f};

  int r0 = m0 + w * 32 + mq;         // rf=0 row for this lane
  int r1 = r0 + 16;                  // rf=1 row
  const float* sr0 = S + (size_t)r0 * KDIM;
  const float* sr1 = S + (size_t)r1 * KDIM;
  // frag-slot base (ushort units)
  size_t sb = (((size_t)mtile * KTILES) * 8 + w * 2) * 1024 + (size_t)lane * 8;

#pragma unroll 2
  for (int t = t0; t < t1; ++t) {
    short8 a00, a01, a10, a11;       // a[rf][kk]
    size_t st = sb + (size_t)t * 8192;
    if (FIRST) {
      int kb = t * 64 + quad * 8;
      a00 = a01 = a10 = a11 = (short8){0, 0, 0, 0, 0, 0, 0, 0};
      {
        int k = kb;
        if (r0 < KDIM && k < KDIM)
          a00 = cvt8(__builtin_nontemporal_load((const floatx4*)(sr0 + k)),
                     __builtin_nontemporal_load((const floatx4*)(sr0 + k + 4)));
        k = kb + 32;
        if (r0 < KDIM && k < KDIM)
          a01 = cvt8(__builtin_nontemporal_load((const floatx4*)(sr0 + k)),
                     __builtin_nontemporal_load((const floatx4*)(sr0 + k + 4)));
        k = kb;
        if (r1 < KDIM && k < KDIM)
          a10 = cvt8(__builtin_nontemporal_load((const floatx4*)(sr1 + k)),
                     __builtin_nontemporal_load((const floatx4*)(sr1 + k + 4)));
        k = kb + 32;
        if (r1 < KDIM && k < KDIM)
          a11 = cvt8(__builtin_nontemporal_load((const floatx4*)(sr1 + k)),
                     __builtin_nontemporal_load((const floatx4*)(sr1 + k + 4)));
      }
      *(short8*)&Sbf[st]        = a00;   // (rf=0,kk=0)
      *(short8*)&Sbf[st + 512]  = a01;   // (rf=0,kk=1)
      *(short8*)&Sbf[st + 1024] = a10;   // (rf=1,kk=0)
      *(short8*)&Sbf[st + 1536] = a11;   // (rf=1,kk=1)
    } else {
      a00 = *(const short8*)&Sbf[st];
      a01 = *(const short8*)&Sbf[st + 512];
      a10 = *(const short8*)&Sbf[st + 1024];
      a11 = *(const short8*)&Sbf[st + 1536];
    }
    const unsigned short* bfb = Bf + (size_t)t * 8192 + lane * 8;
#pragma unroll
    for (int kk = 0; kk < 2; kk++) {
      short8 b[8];
#pragma unroll
      for (int nt = 0; nt < 8; nt++)
        b[nt] = *(const short8*)&bfb[((size_t)nt * 2 + kk) * 512];
      short8 ax0 = kk ? a01 : a00;
      short8 ax1 = kk ? a11 : a10;
#pragma unroll
      for (int nt = 0; nt < 8; nt++) {
        acc[0][nt] = __builtin_amdgcn_mfma_f32_16x16x32_bf16(ax0, b[nt], acc[0][nt], 0, 0, 0);
        acc[1][nt] = __builtin_amdgcn_mfma_f32_16x16x32_bf16(ax1, b[nt], acc[1][nt], 0, 0, 0);
      }
    }
  }
  // epilogue: plain stores to this block's private partial tile (no atomics)
  float* cp = Cpart + ((size_t)ks * MTILES + mtile) * 16384;
#pragma unroll
  for (int rf = 0; rf < 2; rf++) {
#pragma unroll
    for (int nt = 0; nt < 8; nt++) {
      int col = nt * 16 + mq;
      int rb = w * 32 + rf * 16 + quad * 4;
#pragma unroll
      for (int i = 0; i < 4; i++)
        cp[(size_t)(rb + i) * 128 + col] = acc[rf][nt][i];
    }
  }
}

// ---------------- ui SpMM: bf16-packed gather table, f32 Eacc ----------------
template<int LAST>
__global__ __launch_bounds__(256)
void ui_hop(const int* __restrict__ offs, const int2* __restrict__ edges,
            const unsigned* __restrict__ Ebin, unsigned* __restrict__ Ebout,
            float* __restrict__ Eacc) {
  int wid = blockIdx.x * 4 + (threadIdx.x >> 6);   // row id, grid covers exactly 50000
  int lane = threadIdx.x & 63;
  const unsigned* Einl = Ebin + lane;
  int s = offs[wid], e = offs[wid + 1];
  float ax = 0.f, ay = 0.f;
  int j = s;
  for (; j + 4 <= e; j += 4) {
    int2 e0 = edges[j], e1 = edges[j + 1], e2 = edges[j + 2], e3 = edges[j + 3];
    unsigned u0 = Einl[(size_t)e0.x * 64];
    unsigned u1 = Einl[(size_t)e1.x * 64];
    unsigned u2 = Einl[(size_t)e2.x * 64];
    unsigned u3 = Einl[(size_t)e3.x * 64];
    float w0 = __int_as_float(e0.y), w1 = __int_as_float(e1.y);
    float w2 = __int_as_float(e2.y), w3 = __int_as_float(e3.y);
    ax += w0 * __uint_as_float(u0 << 16) + w1 * __uint_as_float(u1 << 16)
        + w2 * __uint_as_float(u2 << 16) + w3 * __uint_as_float(u3 << 16);
    ay += w0 * __uint_as_float(u0 & 0xffff0000u) + w1 * __uint_as_float(u1 & 0xffff0000u)
        + w2 * __uint_as_float(u2 & 0xffff0000u) + w3 * __uint_as_float(u3 & 0xffff0000u);
  }
  for (; j < e; ++j) {
    int2 ed = edges[j];
    unsigned u = Einl[(size_t)ed.x * 64];
    float w = __int_as_float(ed.y);
    ax += w * __uint_as_float(u << 16);
    ay += w * __uint_as_float(u & 0xffff0000u);
  }
  if (!LAST) Ebout[(size_t)wid * 64 + lane] = packbf2(ax, ay);
  size_t op = (size_t)wid * 128 + lane * 2;
  float2 a = *(float2*)&Eacc[op];
  a.x += ax; a.y += ay;
  *(float2*)&Eacc[op] = a;
}

// ---------------- between-hop prep: B-frag from partial-sum | HSacc += partial-sum ----------------
__global__ __launch_bounds__(256)
void prep_kernel(const float* __restrict__ Cpart, unsigned short* __restrict__ Bf,
                 float* __restrict__ HSacc) {
  __shared__ __align__(16) float ts[64 * 132];
  if (blockIdx.x < KTILES) {
    bfrag_from_parts(blockIdx.x, Cpart, Bf, ts);
  } else {
    int i = (blockIdx.x - KTILES) * 256 + threadIdx.x;   // float4 over 10000*128/4
    if (i < (N_USERS * 128) / 4) {
      int r = i >> 5, c = (i & 31) * 4;
      const float* p = Cpart + (size_t)(r >> 7) * 16384 + (size_t)(r & 127) * 128 + c;
      float4 v = make_float4(0.f, 0.f, 0.f, 0.f);
#pragma unroll
      for (int ks = 0; ks < SPLITK; ks++) {
        float4 q = *(const float4*)p; p += CP_STRIDE;
        v.x += q.x; v.y += q.y; v.z += q.z; v.w += q.w;
      }
      float4 a = ((float4*)HSacc)[i];
      a.x += v.x; a.y += v.y; a.z += v.z; a.w += v.w;
      ((float4*)HSacc)[i] = a;
    }
  }
}

// final hop-2 reduce: HSacc += partial-sum (no frag build needed)
__global__ __launch_bounds__(256)
void reduce2(const float* __restrict__ Cpart, float* __restrict__ HSacc) {
  int i = blockIdx.x * 256 + threadIdx.x;   // float4 over 10000*128/4
  if (i < (N_USERS * 128) / 4) {
    int r = i >> 5, c = (i & 31) * 4;
    const float* p = Cpart + (size_t)(r >> 7) * 16384 + (size_t)(r & 127) * 128 + c;
    float4 v = make_float4(0.f, 0.f, 0.f, 0.f);
#pragma unroll
    for (int ks = 0; ks < SPLITK; ks++) {
      float4 q = *(const float4*)p; p += CP_STRIDE;
      v.x += q.x; v.y += q.y; v.z += q.z; v.w += q.w;
    }
    float4 a = ((float4*)HSacc)[i];
    a.x += v.x; a.y += v.y; a.z += v.z; a.w += v.w;
    ((float4*)HSacc)[i] = a;
  }
}

// ---------------- fused outputs ----------------
__global__ __launch_bounds__(256)
void out_kernel(const int* __restrict__ users, const int* __restrict__ pos,
                const int* __restrict__ neg, const float* __restrict__ HSacc,
                const float* __restrict__ Eacc, const float* __restrict__ item1,
                float* __restrict__ out) {
  if (blockIdx.x < 2500) {
    int i = blockIdx.x * 256 + threadIdx.x;         // over 10000*64
    int r = i >> 6, c = i & 63;
    out[O3 + i] = HSacc[(size_t)r * 128 + c] * 0.25f;
    out[O4 + i] = Eacc[(size_t)r * 128 + c] * 0.25f;
  } else {
    int b = (blockIdx.x - 2500) * 4 + (threadIdx.x >> 6);  // 0..8191
    int lane = threadIdx.x & 63;
    int u = users[b], p = pos[b], n = neg[b];
    const float q = 0.25f;
    float us = HSacc[(size_t)u * 128 + lane] * q;
    float ua = Eacc[(size_t)u * 128 + lane] * q;
    size_t bl = (size_t)b * 64 + lane;
    out[O0 + bl]  = 0.5f * (us + ua);
    out[O1 + bl]  = Eacc[(size_t)(N_USERS + p) * 128 + lane] * q;
    out[O2 + bl]  = Eacc[(size_t)(N_USERS + n) * 128 + lane] * q;
    out[O5 + bl]  = HSacc[(size_t)u * 128 + 64 + lane] * q;
    out[O6 + bl]  = item1[(size_t)p * 64 + lane];
    out[O7 + bl]  = item1[(size_t)n * 64 + lane];
    out[O8 + bl]  = Eacc[(size_t)u * 128 + 64 + lane] * q;
    out[O9 + bl]  = Eacc[(size_t)(N_USERS + p) * 128 + 64 + lane] * q;
    out[O10 + bl] = Eacc[(size_t)(N_USERS + n) * 128 + 64 + lane] * q;
  }
}

extern "C" void kernel_launch(void* const* d_in, const int* in_sizes, int n_in,
                              void* d_out, int out_size, void* d_ws, size_t ws_size,
                              hipStream_t stream) {
  (void)n_in; (void)out_size; (void)ws_size;
  const int*   users = (const int*)d_in[0];
  const int*   pos   = (const int*)d_in[1];
  const int*   neg   = (const int*)d_in[2];
  const float* ue    = (const float*)d_in[3];
  const float* ie    = (const float*)d_in[4];
  const float* u1    = (const float*)d_in[5];
  const float* i1    = (const float*)d_in[6];
  const float* u2    = (const float*)d_in[7];
  const float* i2    = (const float*)d_in[8];
  const float* S     = (const float*)d_in[9];
  const int*   Arows = (const int*)d_in[10];
  const int*   Acols = (const int*)d_in[11];
  const float* Avals = (const float*)d_in[12];
  const int nnz = in_sizes[10];

  char* ws = (char*)d_ws;
  size_t off = 0;
  auto alloc = [&](size_t b) { size_t r = off; off += (b + 255) & ~(size_t)255; return r; };
  float* HS0   = (float*)(ws + alloc(sizeof(float) * (size_t)N_USERS * 128));
  float* HSacc = (float*)(ws + alloc(sizeof(float) * (size_t)N_USERS * 128));
  unsigned short* Bf  = (unsigned short*)(ws + alloc(sizeof(short) * (size_t)KTILES * 8192));
  unsigned short* Sbf = (unsigned short*)(ws + alloc(sizeof(short) * (size_t)MTILES * KTILES * 8192));
  float* Cpart = (float*)(ws + alloc(sizeof(float) * (size_t)SPLITK * CP_STRIDE));
  unsigned* Eb0 = (unsigned*)(ws + alloc(sizeof(unsigned) * (size_t)N_TOTAL * 64));
  unsigned* Eb1 = (unsigned*)(ws + alloc(sizeof(unsigned) * (size_t)N_TOTAL * 64));
  float* Eacc  = (float*)(ws + alloc(sizeof(float) * (size_t)N_TOTAL * 128));
  int* counts  = (int*)(ws + alloc(sizeof(int) * (N_TOTAL + 16)));
  int* offs    = (int*)(ws + alloc(sizeof(int) * (N_TOTAL + 16)));
  int* cursor  = (int*)(ws + alloc(sizeof(int) * (N_TOTAL + 16)));
  int* bsum    = (int*)(ws + alloc(sizeof(int) * 256));
  int2* edges  = (int2*)(ws + alloc(sizeof(int2) * (size_t)nnz));

  const int histB = (nnz + 255) / 256;

  hipMemsetAsync(counts, 0, sizeof(int) * (N_TOTAL + 16), stream);
  // init social/ui ego tensors + row histogram, one kernel
  init_all<<<8750 + histB, 256, 0, stream>>>(ue, u1, ie, u2, i2, Arows, counts, nnz,
                                             HS0, HSacc, Eb0, Eacc);
  scan1<<<49, 256, 0, stream>>>(counts, offs, bsum);
  scan2<<<1, 64, 0, stream>>>(bsum, 49);
  // finalize CSR offsets + build hop-0 B-frags from HS0 (independent; fused)
  scan3_bf<<<196 + KTILES, 256, 0, stream>>>(offs, bsum, cursor, nnz, HS0, Bf);
  scatter_csr<<<histB, 256, 0, stream>>>(Arows, Acols, Avals, cursor, edges, nnz);

  // hop 0: ui (bf16 gather), then social (streams S alone, fills Sbf, stores partials)
  ui_hop<0><<<12500, 256, 0, stream>>>(offs, edges, Eb0, Eb1, Eacc);
  social_gemm<1><<<NSOC, 256, 0, stream>>>(S, Sbf, Bf, Cpart);
  // prep: Bf <- frag(sum partials); HSacc += sum partials
  prep_kernel<<<KTILES + 1250, 256, 0, stream>>>(Cpart, Bf, HSacc);
  // hop 1
  ui_hop<0><<<12500, 256, 0, stream>>>(offs, edges, Eb1, Eb0, Eacc);
  social_gemm<0><<<NSOC, 256, 0, stream>>>(S, Sbf, Bf, Cpart);
  prep_kernel<<<KTILES + 1250, 256, 0, stream>>>(Cpart, Bf, HSacc);
  // hop 2
  ui_hop<1><<<12500, 256, 0, stream>>>(offs, edges, Eb0, Eb1, Eacc);
  social_gemm<0><<<NSOC, 256, 0, stream>>>(S, Sbf, Bf, Cpart);
  reduce2<<<1250, 256, 0, stream>>>(Cpart, HSacc);

  float* out = (float*)d_out;
  out_kernel<<<2500 + 2048, 256, 0, stream>>>(users, pos, neg, HSacc, Eacc, i1, out);
}